// Round 2
// baseline (319.455 us; speedup 1.0000x reference)
//
#include <hip/hip_runtime.h>
#include <hip/hip_cooperative_groups.h>
#include <hip/hip_bf16.h>
#include <hip/hip_fp16.h>

namespace cg = cooperative_groups;

// GCN 2-layer: out = Ahat * relu(Ahat*(X W1)+b1) * W2 + b2
// Round 15: consolidate build into ONE cooperative kernel (5 launches -> 1),
// LDS-staged coalesced csr_src writeout, float4 LDS reads in both GEMMs.
//  - build_coop: 256 blocks x 1024 thr, phases {hist, col-scan, total-scan,
//    place, bucket-CSR} separated by grid.sync(). Bucket phase sorts the
//    bucket's ~8.2K edges into a 48KB LDS stage then writes csr_src
//    coalesced (fallback to scattered path if bucket > 12288 padded).
//  - gemm64/gemm32h: k-unrolled x4, float4 LDS reads for As and Ws
//    (17 scalar ds_read per 16 FMA -> ~4.25). FMA order per output
//    unchanged -> bitwise-identical results.
//  - agg64/agg32 unchanged from R14 (proven insensitive to instr count).

#define N_FEAT_IN 64
#define B2SHIFT 9        // 512 dst nodes per coarse bucket
#define NBLK 256         // cooperative grid size == #chunks == #scan columns
#define PADSTRIDE 3592   // per-bucket csr slack: 512 rows * 7 max pad, 8-aligned
#define STCAP 12288      // LDS stage capacity (ints); bucket avg ~8.2K+3.5K pad

struct alignas(8) half4 { __half2 lo, hi; };
struct alignas(16) half8 { __half2 h[4]; };

// ---- one-shot build: hist -> scans -> place -> per-bucket CSR ----
__global__ __launch_bounds__(1024) void build_coop(
    const int* __restrict__ src, const int* __restrict__ dst,
    int* __restrict__ H, int* __restrict__ ctot, int* __restrict__ cbase,
    int* __restrict__ bbase, unsigned* __restrict__ bedges,
    int* __restrict__ row_ptr, int* __restrict__ rend,
    float* __restrict__ dinv, int* __restrict__ csr_src,
    int n, int E, int NB)
{
    cg::grid_group grid = cg::this_grid();
    __shared__ int smem[1024 + STCAP];   // 53248 B
    const int t = threadIdx.x;
    const int b = blockIdx.x;
    const int EC = (E + NBLK - 1) / NBLK;
    const int base = b * EC, endE = min(base + EC, E);

    // phase 1: per-chunk bucket histogram
    if (t < 256) smem[t] = 0;
    __syncthreads();
    for (int i = base + t; i < endE; i += 1024)
        atomicAdd(&smem[dst[i] >> B2SHIFT], 1);
    __syncthreads();
    if (t < 256) H[b * 256 + t] = smem[t];
    grid.sync();

    // phase 2: per-bucket column scan over chunks (block b = bucket b)
    {
        int v = 0;
        if (t < 256) { v = H[t * 256 + b]; smem[t] = v; }
        __syncthreads();
        for (int off = 1; off < 256; off <<= 1) {
            int a = (t < 256 && t >= off) ? smem[t - off] : 0;
            __syncthreads();
            if (t < 256) smem[t] += a;
            __syncthreads();
        }
        if (t < 256) H[t * 256 + b] = smem[t] - v;   // exclusive within bucket
        if (t == 255) ctot[b] = smem[255];
    }
    grid.sync();

    // phase 3: scan bucket totals -> bucket bases (block 0)
    if (b == 0) {
        int v = 0;
        if (t < 256) { v = ctot[t]; smem[t] = v; }
        __syncthreads();
        for (int off = 1; off < 256; off <<= 1) {
            int a = (t < 256 && t >= off) ? smem[t - off] : 0;
            __syncthreads();
            if (t < 256) smem[t] += a;
            __syncthreads();
        }
        if (t < 256) {
            int e = smem[t] - v;
            cbase[t] = e;
            if (t < NB) bbase[t] = e;
        }
        if (t == 0) { bbase[NB] = E; row_ptr[n] = E; }
    }
    grid.sync();

    // phase 4: place packed edges into per-bucket runs
    if (t < 256) smem[t] = H[b * 256 + t] + cbase[t];
    __syncthreads();
    for (int i = base + t; i < endE; i += 1024) {
        int d = dst[i];
        int p = atomicAdd(&smem[d >> B2SHIFT], 1);   // LDS atomic
        bedges[p] = ((unsigned)src[i] << B2SHIFT) | (unsigned)(d & 511);
    }
    grid.sync();

    // phase 5: per-bucket hist -> padded scan -> row_ptr/rend/dinv -> sorted
    // LDS stage -> coalesced csr_src writeout.
    if (b >= NB) return;
    int* lh    = smem;          // [512]
    int* cur   = smem + 512;    // [512]
    int* stage = smem + 1024;   // [STCAP]
    if (t < 512) lh[t] = 0;
    __syncthreads();
    const int beg = bbase[b], end = bbase[b + 1];
    for (int i = beg + t; i < end; i += 1024)
        atomicAdd(&lh[bedges[i] & 511], 1);
    __syncthreads();
    const int c = (t < 512) ? lh[t] : 0;   // true degree
    __syncthreads();
    const int cp = (c + 7) & ~7;           // padded degree
    if (t < 512) lh[t] = cp;
    __syncthreads();
    for (int off = 1; off < 512; off <<= 1) {
        int a = (t < 512 && t >= off) ? lh[t - off] : 0;
        __syncthreads();
        if (t < 512) lh[t] += a;
        __syncthreads();
    }
    const int padTotal = lh[511];
    const int pb = ((beg + 7) & ~7) + b * PADSTRIDE;
    int rbeg = 0;
    if (t < 512) {
        int d = (b << B2SHIFT) + t;
        rbeg = pb + lh[t] - cp;            // 8-aligned padded row start
        if (d < n) {
            row_ptr[d] = rbeg;
            rend[d] = rbeg + cp;
            dinv[d] = rsqrtf((float)c + 1.0f);
        }
    }
    __syncthreads();
    if (padTotal <= STCAP) {
        if (t < 512) cur[t] = rbeg - pb;   // local padded offset
        for (int i = t; i < padTotal; i += 1024) stage[i] = n;  // pad -> zero row
        __syncthreads();
        for (int i = beg + t; i < end; i += 1024) {
            unsigned v = bedges[i];
            int p = atomicAdd(&cur[v & 511], 1);
            stage[p] = (int)(v >> B2SHIFT);
        }
        __syncthreads();
        for (int i = t; i < padTotal; i += 1024)
            csr_src[pb + i] = stage[i];    // fully coalesced
    } else {                               // fallback: direct scatter
        if (t < 512) {
            cur[t] = rbeg;
            int d = (b << B2SHIFT) + t;
            if (d < n)
                for (int i = c; i < cp; ++i) csr_src[rbeg + i] = n;
        }
        __syncthreads();
        for (int i = beg + t; i < end; i += 1024) {
            unsigned v = bedges[i];
            int p = atomicAdd(&cur[v & 511], 1);
            csr_src[p] = (int)(v >> B2SHIFT);
        }
    }
}

// ---- GEMM layer1: xs1[n+1,64] fp16 = half( dinv[row] * (X W1) ); pad row 0 ----
__global__ __launch_bounds__(256) void gemm64(const float* __restrict__ A,
                                              const float* __restrict__ W,
                                              const float* __restrict__ dinv,
                                              __half* __restrict__ outh, int n) {
    constexpr int K = 64, FO = 64, CPT = 16;
    __shared__ float As[64][K + 4];
    __shared__ float Ws[K][FO];

    const int t = threadIdx.x;
    const int r0 = blockIdx.x * 64;

    if (blockIdx.x == 0 && t < FO)
        outh[(size_t)n * FO + t] = __float2half(0.f);

    for (int i = t; i < K * FO / 4; i += 256) {
        int k = i / (FO / 4);
        int c4 = (i % (FO / 4)) * 4;
        *(float4*)&Ws[k][c4] = *(const float4*)&W[k * FO + c4];
    }
    for (int i = t; i < 1024; i += 256) {
        int row = i / 16;
        int c4 = (i % 16) * 4;
        int g = r0 + row;
        float4 v = make_float4(0.f, 0.f, 0.f, 0.f);
        if (g < n) v = *(const float4*)&A[(size_t)g * K + c4];
        *(float4*)&As[row][c4] = v;
    }
    __syncthreads();

    const int row = t >> 2;
    const int c0 = (t & 3) * CPT;
    float acc[CPT];
#pragma unroll
    for (int j = 0; j < CPT; ++j) acc[j] = 0.f;
#pragma unroll
    for (int k4 = 0; k4 < K; k4 += 4) {
        float4 xv4 = *(const float4*)&As[row][k4];
#pragma unroll
        for (int kk = 0; kk < 4; ++kk) {
            float xv = (kk == 0) ? xv4.x : (kk == 1) ? xv4.y : (kk == 2) ? xv4.z : xv4.w;
            float4 w0 = *(const float4*)&Ws[k4 + kk][c0];
            float4 w1 = *(const float4*)&Ws[k4 + kk][c0 + 4];
            float4 w2 = *(const float4*)&Ws[k4 + kk][c0 + 8];
            float4 w3 = *(const float4*)&Ws[k4 + kk][c0 + 12];
            acc[0]  = fmaf(xv, w0.x, acc[0]);
            acc[1]  = fmaf(xv, w0.y, acc[1]);
            acc[2]  = fmaf(xv, w0.z, acc[2]);
            acc[3]  = fmaf(xv, w0.w, acc[3]);
            acc[4]  = fmaf(xv, w1.x, acc[4]);
            acc[5]  = fmaf(xv, w1.y, acc[5]);
            acc[6]  = fmaf(xv, w1.z, acc[6]);
            acc[7]  = fmaf(xv, w1.w, acc[7]);
            acc[8]  = fmaf(xv, w2.x, acc[8]);
            acc[9]  = fmaf(xv, w2.y, acc[9]);
            acc[10] = fmaf(xv, w2.z, acc[10]);
            acc[11] = fmaf(xv, w2.w, acc[11]);
            acc[12] = fmaf(xv, w3.x, acc[12]);
            acc[13] = fmaf(xv, w3.y, acc[13]);
            acc[14] = fmaf(xv, w3.z, acc[14]);
            acc[15] = fmaf(xv, w3.w, acc[15]);
        }
    }

    int g = r0 + row;
    if (g < n) {
        float sc = dinv[g];
#pragma unroll
        for (int j4 = 0; j4 < CPT; j4 += 4) {
            half4 h;
            h.lo = __floats2half2_rn(acc[j4] * sc, acc[j4 + 1] * sc);
            h.hi = __floats2half2_rn(acc[j4 + 2] * sc, acc[j4 + 3] * sc);
            *(half4*)&outh[(size_t)g * FO + c0 + j4] = h;
        }
    }
}

#define ACC8(v)                                                       \
    {                                                                 \
        float2 f0 = __half22float2((v).h[0]);                         \
        float2 f1 = __half22float2((v).h[1]);                         \
        float2 f2 = __half22float2((v).h[2]);                         \
        float2 f3 = __half22float2((v).h[3]);                         \
        a0 += f0.x; a1 += f0.y; a2 += f1.x; a3 += f1.y;               \
        a4 += f2.x; a5 += f2.y; a6 += f3.x; a7 += f3.y;               \
    }

// ---- agg64: 8 rows/wave, 8 lanes/row, half8/lane; t = relu(dinv*acc+b1) ----
__global__ __launch_bounds__(256) void agg64(const int* __restrict__ row_ptr,
                                             const int* __restrict__ rend,
                                             const int* __restrict__ csr_src,
                                             const float* __restrict__ dinv,
                                             const __half* __restrict__ xs1,
                                             const float* __restrict__ b1,
                                             __half* __restrict__ th, int n) {
    int d = blockIdx.x * 32 + (threadIdx.x >> 3);  // 32 rows/block
    if (d >= n) return;
    int c = threadIdx.x & 7;                       // half8 slice (feats 8c..8c+7)
    const half8* __restrict__ xrow = (const half8*)xs1 + c;  // row stride 8 half8

    half8 sv = xrow[(size_t)d * 8];                // self-loop
    float a0, a1, a2, a3, a4, a5, a6, a7;
    {
        float2 f0 = __half22float2(sv.h[0]), f1 = __half22float2(sv.h[1]);
        float2 f2 = __half22float2(sv.h[2]), f3 = __half22float2(sv.h[3]);
        a0 = f0.x; a1 = f0.y; a2 = f1.x; a3 = f1.y;
        a4 = f2.x; a5 = f2.y; a6 = f3.x; a7 = f3.y;
    }

    int beg = row_ptr[d];
    int end = rend[d];
    if (beg < end) {
        int4 ia = *(const int4*)&csr_src[beg];
        int4 ib = *(const int4*)&csr_src[beg + 4];
        int jb = beg;
        for (;;) {
            int jn = jb + 8;
            bool more = jn < end;
            int js = more ? jn : beg;              // prefetch next batch
            int4 na = *(const int4*)&csr_src[js];
            int4 nb = *(const int4*)&csr_src[js + 4];
            half8 v0 = xrow[(size_t)ia.x * 8];
            half8 v1 = xrow[(size_t)ia.y * 8];
            half8 v2 = xrow[(size_t)ia.z * 8];
            half8 v3 = xrow[(size_t)ia.w * 8];
            half8 v4 = xrow[(size_t)ib.x * 8];
            half8 v5 = xrow[(size_t)ib.y * 8];
            half8 v6 = xrow[(size_t)ib.z * 8];
            half8 v7 = xrow[(size_t)ib.w * 8];
            ACC8(v0); ACC8(v1); ACC8(v2); ACC8(v3);
            ACC8(v4); ACC8(v5); ACC8(v6); ACC8(v7);
            if (!more) break;
            jb = jn; ia = na; ib = nb;
        }
    }

    float di = dinv[d];
    float4 ba = *(const float4*)&b1[8 * c];
    float4 bb = *(const float4*)&b1[8 * c + 4];
    float t0 = fmaxf(fmaf(di, a0, ba.x), 0.f);
    float t1 = fmaxf(fmaf(di, a1, ba.y), 0.f);
    float t2 = fmaxf(fmaf(di, a2, ba.z), 0.f);
    float t3 = fmaxf(fmaf(di, a3, ba.w), 0.f);
    float t4 = fmaxf(fmaf(di, a4, bb.x), 0.f);
    float t5 = fmaxf(fmaf(di, a5, bb.y), 0.f);
    float t6 = fmaxf(fmaf(di, a6, bb.z), 0.f);
    float t7 = fmaxf(fmaf(di, a7, bb.w), 0.f);
    half8 o;
    o.h[0] = __floats2half2_rn(t0, t1);
    o.h[1] = __floats2half2_rn(t2, t3);
    o.h[2] = __floats2half2_rn(t4, t5);
    o.h[3] = __floats2half2_rn(t6, t7);
    *(half8*)&th[(size_t)d * 64 + 8 * c] = o;
}

// ---- gemm32h: xs2[n+1,32] fp16 = half( dinv[row] * (t[n,64] W2) ); pad row ----
__global__ __launch_bounds__(256) void gemm32h(const __half* __restrict__ Ah,
                                               const float* __restrict__ W,
                                               const float* __restrict__ dinv,
                                               __half* __restrict__ outh, int n) {
    constexpr int K = 64, FO = 32, CPT = 8;
    __shared__ float As[64][K + 4];
    __shared__ float Ws[K][FO];

    const int t = threadIdx.x;
    const int r0 = blockIdx.x * 64;

    if (blockIdx.x == 0 && t < FO)
        outh[(size_t)n * FO + t] = __float2half(0.f);

    for (int i = t; i < K * FO / 4; i += 256) {
        int k = i / (FO / 4);
        int c4 = (i % (FO / 4)) * 4;
        *(float4*)&Ws[k][c4] = *(const float4*)&W[k * FO + c4];
    }
    for (int i = t; i < 1024; i += 256) {
        int row = i / 16;
        int c4 = (i % 16) * 4;
        int g = r0 + row;
        float4 v = make_float4(0.f, 0.f, 0.f, 0.f);
        if (g < n) {
            half4 hv = *(const half4*)&Ah[(size_t)g * K + c4];
            float2 lo = __half22float2(hv.lo), hi = __half22float2(hv.hi);
            v = make_float4(lo.x, lo.y, hi.x, hi.y);
        }
        *(float4*)&As[row][c4] = v;
    }
    __syncthreads();

    const int row = t >> 2;
    const int c0 = (t & 3) * CPT;
    float acc[CPT];
#pragma unroll
    for (int j = 0; j < CPT; ++j) acc[j] = 0.f;
#pragma unroll
    for (int k4 = 0; k4 < K; k4 += 4) {
        float4 xv4 = *(const float4*)&As[row][k4];
#pragma unroll
        for (int kk = 0; kk < 4; ++kk) {
            float xv = (kk == 0) ? xv4.x : (kk == 1) ? xv4.y : (kk == 2) ? xv4.z : xv4.w;
            float4 w0 = *(const float4*)&Ws[k4 + kk][c0];
            float4 w1 = *(const float4*)&Ws[k4 + kk][c0 + 4];
            acc[0] = fmaf(xv, w0.x, acc[0]);
            acc[1] = fmaf(xv, w0.y, acc[1]);
            acc[2] = fmaf(xv, w0.z, acc[2]);
            acc[3] = fmaf(xv, w0.w, acc[3]);
            acc[4] = fmaf(xv, w1.x, acc[4]);
            acc[5] = fmaf(xv, w1.y, acc[5]);
            acc[6] = fmaf(xv, w1.z, acc[6]);
            acc[7] = fmaf(xv, w1.w, acc[7]);
        }
    }

    int g = r0 + row;
    if (g < n) {
        float sc = dinv[g];
#pragma unroll
        for (int j4 = 0; j4 < CPT; j4 += 4) {
            half4 h;
            h.lo = __floats2half2_rn(acc[j4] * sc, acc[j4 + 1] * sc);
            h.hi = __floats2half2_rn(acc[j4 + 2] * sc, acc[j4 + 3] * sc);
            *(half4*)&outh[(size_t)g * FO + c0 + j4] = h;
        }
    }
}

// ---- agg32: 16 rows/wave, 4 lanes/row, half8/lane; out = dinv*acc + b2 ----
__global__ __launch_bounds__(256) void agg32(const int* __restrict__ row_ptr,
                                             const int* __restrict__ rend,
                                             const int* __restrict__ csr_src,
                                             const float* __restrict__ dinv,
                                             const __half* __restrict__ xs2,
                                             const float* __restrict__ b2,
                                             float* __restrict__ out, int n) {
    int d = blockIdx.x * 64 + (threadIdx.x >> 2);  // 64 rows/block
    if (d >= n) return;
    int c = threadIdx.x & 3;                       // half8 slice (feats 8c..8c+7)
    const half8* __restrict__ xrow = (const half8*)xs2 + c;  // row stride 4 half8

    half8 sv = xrow[(size_t)d * 4];                // self-loop
    float a0, a1, a2, a3, a4, a5, a6, a7;
    {
        float2 f0 = __half22float2(sv.h[0]), f1 = __half22float2(sv.h[1]);
        float2 f2 = __half22float2(sv.h[2]), f3 = __half22float2(sv.h[3]);
        a0 = f0.x; a1 = f0.y; a2 = f1.x; a3 = f1.y;
        a4 = f2.x; a5 = f2.y; a6 = f3.x; a7 = f3.y;
    }

    int beg = row_ptr[d];
    int end = rend[d];
    if (beg < end) {
        int4 ia = *(const int4*)&csr_src[beg];
        int4 ib = *(const int4*)&csr_src[beg + 4];
        int jb = beg;
        for (;;) {
            int jn = jb + 8;
            bool more = jn < end;
            int js = more ? jn : beg;
            int4 na = *(const int4*)&csr_src[js];
            int4 nb = *(const int4*)&csr_src[js + 4];
            half8 v0 = xrow[(size_t)ia.x * 4];
            half8 v1 = xrow[(size_t)ia.y * 4];
            half8 v2 = xrow[(size_t)ia.z * 4];
            half8 v3 = xrow[(size_t)ia.w * 4];
            half8 v4 = xrow[(size_t)ib.x * 4];
            half8 v5 = xrow[(size_t)ib.y * 4];
            half8 v6 = xrow[(size_t)ib.z * 4];
            half8 v7 = xrow[(size_t)ib.w * 4];
            ACC8(v0); ACC8(v1); ACC8(v2); ACC8(v3);
            ACC8(v4); ACC8(v5); ACC8(v6); ACC8(v7);
            if (!more) break;
            jb = jn; ia = na; ib = nb;
        }
    }

    float di = dinv[d];
    float4 ba = *(const float4*)&b2[8 * c];
    float4 bb = *(const float4*)&b2[8 * c + 4];
    float4 r0, r1;
    r0.x = fmaf(di, a0, ba.x);
    r0.y = fmaf(di, a1, ba.y);
    r0.z = fmaf(di, a2, ba.z);
    r0.w = fmaf(di, a3, ba.w);
    r1.x = fmaf(di, a4, bb.x);
    r1.y = fmaf(di, a5, bb.y);
    r1.z = fmaf(di, a6, bb.z);
    r1.w = fmaf(di, a7, bb.w);
    *(float4*)&out[(size_t)d * 32 + 8 * c] = r0;
    *(float4*)&out[(size_t)d * 32 + 8 * c + 4] = r1;
}

extern "C" void kernel_launch(void* const* d_in, const int* in_sizes, int n_in,
                              void* d_out, int out_size, void* d_ws, size_t ws_size,
                              hipStream_t stream) {
    const float* x  = (const float*)d_in[0];   // [n, 64]
    const int*   ei = (const int*)d_in[1];     // [2, E]
    const float* W1 = (const float*)d_in[2];   // [64, 64]
    const float* b1 = (const float*)d_in[3];   // [64]
    const float* W2 = (const float*)d_in[4];   // [64, 32]
    const float* b2 = (const float*)d_in[5];   // [32]
    float* out = (float*)d_out;                // [n, 32]

    const int n = in_sizes[0] / N_FEAT_IN;     // 100000
    const int E = in_sizes[1] / 2;             // 1600000
    const int* srcI = ei;
    const int* dstI = ei + E;

    const int NB = (n + 511) >> B2SHIFT;       // 196 coarse buckets

    // workspace layout (256B aligned)
    char* ws = (char*)d_ws;
    size_t off = 0;
    auto alloc = [&](size_t bytes) {
        void* p = ws + off;
        off += (bytes + 255) & ~(size_t)255;
        return p;
    };
    float*    dinv    = (float*)alloc((size_t)n * 4);
    int*      row_ptr = (int*)alloc((size_t)(n + 1) * 4);
    int*      rend    = (int*)alloc((size_t)n * 4);
    int*      bbase   = (int*)alloc((size_t)(NB + 1) * 4);
    int*      ctot    = (int*)alloc((size_t)256 * 4);
    int*      cbase   = (int*)alloc((size_t)256 * 4);
    int*      H       = (int*)alloc((size_t)NBLK * 256 * 4);      // 256KB
    unsigned* bedges  = (unsigned*)alloc((size_t)E * 4);
    int*      csr_src = (int*)alloc((size_t)(E + (size_t)NB * PADSTRIDE + 16) * 4);
    __half*   xs1     = (__half*)alloc((size_t)(n + 1) * 64 * 2); // +pad row
    __half*   th      = (__half*)alloc((size_t)n * 64 * 2);       // relu'd t
    __half*   xs2     = (__half*)alloc((size_t)(n + 1) * 32 * 2); // +pad row

    // 1) one-shot cooperative build: sort + row_ptr/rend + dinv + CSR
    {
        int n_ = n, E_ = E, NB_ = NB;
        void* args[] = {
            (void*)&srcI, (void*)&dstI, (void*)&H, (void*)&ctot, (void*)&cbase,
            (void*)&bbase, (void*)&bedges, (void*)&row_ptr, (void*)&rend,
            (void*)&dinv, (void*)&csr_src, (void*)&n_, (void*)&E_, (void*)&NB_};
        hipLaunchCooperativeKernel((const void*)build_coop, dim3(NBLK), dim3(1024),
                                   args, 0, stream);
    }

    // 2) layer 1 GEMM: xs1 = half(dinv .* (X W1))
    gemm64<<<(n + 63) / 64, 256, 0, stream>>>(x, W1, dinv, xs1, n);

    // 3) layer-1 aggregate: t = relu(dinv*(gather+self) + b1)
    agg64<<<(n + 31) / 32, 256, 0, stream>>>(row_ptr, rend, csr_src, dinv, xs1, b1, th, n);

    // 4) layer-2 transform: xs2 = half(dinv .* (t W2))
    gemm32h<<<(n + 63) / 64, 256, 0, stream>>>(th, W2, dinv, xs2, n);

    // 5) layer-2 aggregate -> out
    agg32<<<(n + 63) / 64, 256, 0, stream>>>(row_ptr, rend, csr_src, dinv, xs2, b2, out, n);
}

// Round 3
// 245.356 us; speedup vs baseline: 1.3020x; 1.3020x over previous
//
#include <hip/hip_runtime.h>
#include <hip/hip_bf16.h>
#include <hip/hip_fp16.h>

// GCN 2-layer: out = Ahat * relu(Ahat*(X W1)+b1) * W2 + b2
// Round 16: revert coop build (R15 post-mortem: grid.sync ~100us on 8-XCD).
// Feature-slab L2-resident aggregation:
//  - xs1 stored as 4 slabs [n+1][16] fp16 (3.2MB each), th as 4 slabs [n][16],
//    xs2 as 2 slabs [n+1][16]. Aggregation runs as sequential passes, one slab
//    each; per pass the gather target fits every XCD's 4MB L2 -> gathers hit
//    L2 instead of L3. Same bytes, same accumulation order (bitwise-identical).
//  - agg pass: 4 lanes/row, half4 (8B) gathers, 64 rows/block; 6250 waves/pass
//    (~24/CU) for latency hiding. Padded-CSR batch loop from R14.
//  - build pipeline: R14 verbatim (5 kernels, ~27us total).
//  - gemms: R15 float4-LDS-read bodies, slab-adapted stores/loads.

#define N_FEAT_IN 64
#define B2SHIFT 9        // 512 dst nodes per coarse bucket
#define CHUNK 4096       // edges per block in pass A/B
#define PADSTRIDE 3592   // per-bucket csr slack: 512 rows * 7 max pad, 8-aligned

struct alignas(8) half4 { __half2 lo, hi; };

// ---- pass A: per-chunk bucket histogram (LDS, no global atomics) ----
__global__ __launch_bounds__(1024) void passA_hist(const int* __restrict__ dst,
                                                   int* __restrict__ H, int E) {
    __shared__ int h[256];
    int t = threadIdx.x;
    if (t < 256) h[t] = 0;
    __syncthreads();
    int base = blockIdx.x * CHUNK;
    int end = min(base + CHUNK, E);
    for (int i = base + t; i < end; i += 1024)
        atomicAdd(&h[dst[i] >> B2SHIFT], 1);
    __syncthreads();
    if (t < 256) H[blockIdx.x * 256 + t] = h[t];
}

// ---- col_scan_a: one block per column; exclusive scan over NR rows ----
__global__ __launch_bounds__(512) void col_scan_a(int* __restrict__ H,
                                                  int* __restrict__ ctot, int NR) {
    __shared__ int s[512];
    int b = blockIdx.x;
    int t = threadIdx.x;
    int v = (t < NR) ? H[t * 256 + b] : 0;
    s[t] = v;
    __syncthreads();
    for (int off = 1; off < 512; off <<= 1) {
        int a = (t >= off) ? s[t - off] : 0;
        __syncthreads();
        s[t] += a;
        __syncthreads();
    }
    if (t < NR) H[t * 256 + b] = s[t] - v;
    if (t == 511) ctot[b] = s[511];
}

// ---- col_scan_b: scan column totals -> per-bucket bases; row_ptr[n]=E ----
__global__ __launch_bounds__(256) void col_scan_b(const int* __restrict__ ctot,
                                                  int* __restrict__ cbase,
                                                  int* __restrict__ bbase,
                                                  int* __restrict__ row_ptr,
                                                  int NB, int n, int E) {
    __shared__ int s[256];
    int t = threadIdx.x;
    int v = ctot[t];
    s[t] = v;
    __syncthreads();
    for (int off = 1; off < 256; off <<= 1) {
        int a = (t >= off) ? s[t - off] : 0;
        __syncthreads();
        s[t] += a;
        __syncthreads();
    }
    int e = s[t] - v;
    cbase[t] = e;
    if (t < NB) bbase[t] = e;
    if (t == 0) { bbase[NB] = E; row_ptr[n] = E; }
}

// ---- pass B: place packed edges into private per-chunk runs ----
__global__ __launch_bounds__(1024) void passB_place(const int* __restrict__ src,
                                                    const int* __restrict__ dst,
                                                    const int* __restrict__ H,
                                                    const int* __restrict__ cbase,
                                                    unsigned* __restrict__ bedges, int E) {
    __shared__ int cur[256];
    int t = threadIdx.x;
    if (t < 256) cur[t] = H[blockIdx.x * 256 + t] + cbase[t];
    __syncthreads();
    int base = blockIdx.x * CHUNK;
    int end = min(base + CHUNK, E);
    for (int i = base + t; i < end; i += 1024) {
        int d = dst[i];
        int p = atomicAdd(&cur[d >> B2SHIFT], 1);  // LDS atomic
        bedges[p] = ((unsigned)src[i] << B2SHIFT) | (unsigned)(d & 511);
    }
}

// ---- merged: per-bucket hist -> padded scan -> row_ptr/rend/dinv -> scatter ----
__global__ __launch_bounds__(1024) void bucket_csr(const int* __restrict__ bbase,
                                                   const unsigned* __restrict__ bedges,
                                                   int* __restrict__ row_ptr,
                                                   int* __restrict__ rend,
                                                   float* __restrict__ dinv,
                                                   int* __restrict__ csr_src, int n) {
    __shared__ int lh[512];
    __shared__ int cur[512];
    int t = threadIdx.x;
    if (t < 512) lh[t] = 0;
    __syncthreads();
    int b = blockIdx.x;
    int beg = bbase[b], end = bbase[b + 1];
    for (int i = beg + t; i < end; i += 1024)
        atomicAdd(&lh[bedges[i] & 511], 1);
    __syncthreads();
    int c = (t < 512) ? lh[t] : 0;       // true degree (no self-loop)
    __syncthreads();
    int cp = (c + 7) & ~7;               // padded degree
    if (t < 512) lh[t] = cp;
    __syncthreads();
    for (int off = 1; off < 512; off <<= 1) {
        int a = (t < 512 && t >= off) ? lh[t - off] : 0;
        __syncthreads();
        if (t < 512) lh[t] += a;
        __syncthreads();
    }
    int pb = ((beg + 7) & ~7) + b * PADSTRIDE;
    if (t < 512) {
        int d = (b << B2SHIFT) + t;
        int rbeg = pb + lh[t] - cp;      // 8-aligned exclusive padded offset
        cur[t] = rbeg;
        if (d < n) {
            row_ptr[d] = rbeg;
            rend[d] = rbeg + cp;
            dinv[d] = rsqrtf((float)c + 1.0f);
            for (int i = c; i < cp; ++i) csr_src[rbeg + i] = n;  // pad -> zero row
        }
    }
    __syncthreads();
    for (int i = beg + t; i < end; i += 1024) {
        unsigned v = bedges[i];
        int p = atomicAdd(&cur[v & 511], 1);  // LDS atomic
        csr_src[p] = (int)(v >> B2SHIFT);
    }
}

// ---- GEMM layer1: xs1 slabs[4][n+1][16] fp16 = half( dinv[row]*(X W1) ) ----
__global__ __launch_bounds__(256) void gemm64(const float* __restrict__ A,
                                              const float* __restrict__ W,
                                              const float* __restrict__ dinv,
                                              __half* __restrict__ xs1, int n) {
    constexpr int K = 64, FO = 64, CPT = 16;
    __shared__ float As[64][K + 4];
    __shared__ float Ws[K][FO];

    const int t = threadIdx.x;
    const int r0 = blockIdx.x * 64;
    const size_t slabE = (size_t)(n + 1) * 16;

    if (blockIdx.x == 0 && t < FO)   // zero pad row in all 4 slabs
        xs1[(size_t)(t >> 4) * slabE + (size_t)n * 16 + (t & 15)] = __float2half(0.f);

    for (int i = t; i < K * FO / 4; i += 256) {
        int k = i / (FO / 4);
        int c4 = (i % (FO / 4)) * 4;
        *(float4*)&Ws[k][c4] = *(const float4*)&W[k * FO + c4];
    }
    for (int i = t; i < 1024; i += 256) {
        int row = i / 16;
        int c4 = (i % 16) * 4;
        int g = r0 + row;
        float4 v = make_float4(0.f, 0.f, 0.f, 0.f);
        if (g < n) v = *(const float4*)&A[(size_t)g * K + c4];
        *(float4*)&As[row][c4] = v;
    }
    __syncthreads();

    const int row = t >> 2;
    const int c0 = (t & 3) * CPT;
    float acc[CPT];
#pragma unroll
    for (int j = 0; j < CPT; ++j) acc[j] = 0.f;
#pragma unroll
    for (int k4 = 0; k4 < K; k4 += 4) {
        float4 xv4 = *(const float4*)&As[row][k4];
#pragma unroll
        for (int kk = 0; kk < 4; ++kk) {
            float xv = (kk == 0) ? xv4.x : (kk == 1) ? xv4.y : (kk == 2) ? xv4.z : xv4.w;
            float4 w0 = *(const float4*)&Ws[k4 + kk][c0];
            float4 w1 = *(const float4*)&Ws[k4 + kk][c0 + 4];
            float4 w2 = *(const float4*)&Ws[k4 + kk][c0 + 8];
            float4 w3 = *(const float4*)&Ws[k4 + kk][c0 + 12];
            acc[0]  = fmaf(xv, w0.x, acc[0]);
            acc[1]  = fmaf(xv, w0.y, acc[1]);
            acc[2]  = fmaf(xv, w0.z, acc[2]);
            acc[3]  = fmaf(xv, w0.w, acc[3]);
            acc[4]  = fmaf(xv, w1.x, acc[4]);
            acc[5]  = fmaf(xv, w1.y, acc[5]);
            acc[6]  = fmaf(xv, w1.z, acc[6]);
            acc[7]  = fmaf(xv, w1.w, acc[7]);
            acc[8]  = fmaf(xv, w2.x, acc[8]);
            acc[9]  = fmaf(xv, w2.y, acc[9]);
            acc[10] = fmaf(xv, w2.z, acc[10]);
            acc[11] = fmaf(xv, w2.w, acc[11]);
            acc[12] = fmaf(xv, w3.x, acc[12]);
            acc[13] = fmaf(xv, w3.y, acc[13]);
            acc[14] = fmaf(xv, w3.z, acc[14]);
            acc[15] = fmaf(xv, w3.w, acc[15]);
        }
    }

    int g = r0 + row;
    if (g < n) {
        float sc = dinv[g];
#pragma unroll
        for (int j4 = 0; j4 < CPT; j4 += 4) {
            int cc = c0 + j4;
            half4 h;
            h.lo = __floats2half2_rn(acc[j4] * sc, acc[j4 + 1] * sc);
            h.hi = __floats2half2_rn(acc[j4 + 2] * sc, acc[j4 + 3] * sc);
            *(half4*)&xs1[(size_t)(cc >> 4) * slabE + (size_t)g * 16 + (cc & 15)] = h;
        }
    }
}

#define ACC4(v)                                                       \
    {                                                                 \
        float2 f0 = __half22float2((v).lo);                           \
        float2 f1 = __half22float2((v).hi);                           \
        a0 += f0.x; a1 += f0.y; a2 += f1.x; a3 += f1.y;               \
    }

// ---- agg slab pass: 16 feats/slab, 4 lanes/row, half4 (8B) gathers ----
// t = relu(dinv*(gather+self) + b1slice) -> fp16 slab
__global__ __launch_bounds__(256) void agg64s(const int* __restrict__ row_ptr,
                                              const int* __restrict__ rend,
                                              const int* __restrict__ csr_src,
                                              const float* __restrict__ dinv,
                                              const __half* __restrict__ xslab,
                                              const float* __restrict__ b1f,
                                              __half* __restrict__ tslab, int n) {
    int d = blockIdx.x * 64 + (threadIdx.x >> 2);  // 64 rows/block
    if (d >= n) return;
    int c = threadIdx.x & 3;                       // half4 slice (feats 4c..4c+3)
    const half4* __restrict__ xrow = (const half4*)xslab + c;  // row stride 4 half4

    half4 sv = xrow[(size_t)d * 4];                // self-loop
    float a0, a1, a2, a3;
    {
        float2 f0 = __half22float2(sv.lo), f1 = __half22float2(sv.hi);
        a0 = f0.x; a1 = f0.y; a2 = f1.x; a3 = f1.y;
    }

    int beg = row_ptr[d];
    int end = rend[d];
    if (beg < end) {
        int4 ia = *(const int4*)&csr_src[beg];
        int4 ib = *(const int4*)&csr_src[beg + 4];
        int jb = beg;
        for (;;) {
            int jn = jb + 8;
            bool more = jn < end;
            int js = more ? jn : beg;              // prefetch next batch
            int4 na = *(const int4*)&csr_src[js];
            int4 nb = *(const int4*)&csr_src[js + 4];
            half4 v0 = xrow[(size_t)ia.x * 4];
            half4 v1 = xrow[(size_t)ia.y * 4];
            half4 v2 = xrow[(size_t)ia.z * 4];
            half4 v3 = xrow[(size_t)ia.w * 4];
            half4 v4 = xrow[(size_t)ib.x * 4];
            half4 v5 = xrow[(size_t)ib.y * 4];
            half4 v6 = xrow[(size_t)ib.z * 4];
            half4 v7 = xrow[(size_t)ib.w * 4];
            ACC4(v0); ACC4(v1); ACC4(v2); ACC4(v3);
            ACC4(v4); ACC4(v5); ACC4(v6); ACC4(v7);
            if (!more) break;
            jb = jn; ia = na; ib = nb;
        }
    }

    float di = dinv[d];
    float4 bv = *(const float4*)&b1f[4 * c];
    float t0 = fmaxf(fmaf(di, a0, bv.x), 0.f);
    float t1 = fmaxf(fmaf(di, a1, bv.y), 0.f);
    float t2 = fmaxf(fmaf(di, a2, bv.z), 0.f);
    float t3 = fmaxf(fmaf(di, a3, bv.w), 0.f);
    half4 o;
    o.lo = __floats2half2_rn(t0, t1);
    o.hi = __floats2half2_rn(t2, t3);
    *(half4*)&tslab[(size_t)d * 16 + 4 * c] = o;
}

// ---- gemm32h: xs2 slabs[2][n+1][16] fp16 = half( dinv[row]*(t W2) ) ----
__global__ __launch_bounds__(256) void gemm32h(const __half* __restrict__ th,
                                               const float* __restrict__ W,
                                               const float* __restrict__ dinv,
                                               __half* __restrict__ xs2, int n) {
    constexpr int K = 64, FO = 32, CPT = 8;
    __shared__ float As[64][K + 4];
    __shared__ float Ws[K][FO];

    const int t = threadIdx.x;
    const int r0 = blockIdx.x * 64;
    const size_t slabE = (size_t)(n + 1) * 16;
    const size_t tslabE = (size_t)n * 16;

    if (blockIdx.x == 0 && t < FO)   // zero pad row in both slabs
        xs2[(size_t)(t >> 4) * slabE + (size_t)n * 16 + (t & 15)] = __float2half(0.f);

    for (int i = t; i < K * FO / 4; i += 256) {
        int k = i / (FO / 4);
        int c4 = (i % (FO / 4)) * 4;
        *(float4*)&Ws[k][c4] = *(const float4*)&W[k * FO + c4];
    }
    for (int i = t; i < 1024; i += 256) {
        int row = i / 16;
        int c4 = (i % 16) * 4;            // global feat 0..60
        int g = r0 + row;
        float4 v = make_float4(0.f, 0.f, 0.f, 0.f);
        if (g < n) {
            const __half* thp = th + (size_t)(c4 >> 4) * tslabE;
            half4 hv = *(const half4*)&thp[(size_t)g * 16 + (c4 & 15)];
            float2 lo = __half22float2(hv.lo), hi = __half22float2(hv.hi);
            v = make_float4(lo.x, lo.y, hi.x, hi.y);
        }
        *(float4*)&As[row][c4] = v;
    }
    __syncthreads();

    const int row = t >> 2;
    const int c0 = (t & 3) * CPT;
    float acc[CPT];
#pragma unroll
    for (int j = 0; j < CPT; ++j) acc[j] = 0.f;
#pragma unroll
    for (int k4 = 0; k4 < K; k4 += 4) {
        float4 xv4 = *(const float4*)&As[row][k4];
#pragma unroll
        for (int kk = 0; kk < 4; ++kk) {
            float xv = (kk == 0) ? xv4.x : (kk == 1) ? xv4.y : (kk == 2) ? xv4.z : xv4.w;
            float4 w0 = *(const float4*)&Ws[k4 + kk][c0];
            float4 w1 = *(const float4*)&Ws[k4 + kk][c0 + 4];
            acc[0] = fmaf(xv, w0.x, acc[0]);
            acc[1] = fmaf(xv, w0.y, acc[1]);
            acc[2] = fmaf(xv, w0.z, acc[2]);
            acc[3] = fmaf(xv, w0.w, acc[3]);
            acc[4] = fmaf(xv, w1.x, acc[4]);
            acc[5] = fmaf(xv, w1.y, acc[5]);
            acc[6] = fmaf(xv, w1.z, acc[6]);
            acc[7] = fmaf(xv, w1.w, acc[7]);
        }
    }

    int g = r0 + row;
    if (g < n) {
        float sc = dinv[g];
#pragma unroll
        for (int j4 = 0; j4 < CPT; j4 += 4) {
            int cc = c0 + j4;
            half4 h;
            h.lo = __floats2half2_rn(acc[j4] * sc, acc[j4 + 1] * sc);
            h.hi = __floats2half2_rn(acc[j4 + 2] * sc, acc[j4 + 3] * sc);
            *(half4*)&xs2[(size_t)(cc >> 4) * slabE + (size_t)g * 16 + (cc & 15)] = h;
        }
    }
}

// ---- agg32 slab pass: out slice = dinv*(gather+self) + b2 slice ----
__global__ __launch_bounds__(256) void agg32s(const int* __restrict__ row_ptr,
                                              const int* __restrict__ rend,
                                              const int* __restrict__ csr_src,
                                              const float* __restrict__ dinv,
                                              const __half* __restrict__ xslab,
                                              const float* __restrict__ b2s,
                                              float* __restrict__ outp, int n) {
    int d = blockIdx.x * 64 + (threadIdx.x >> 2);  // 64 rows/block
    if (d >= n) return;
    int c = threadIdx.x & 3;                       // half4 slice
    const half4* __restrict__ xrow = (const half4*)xslab + c;

    half4 sv = xrow[(size_t)d * 4];                // self-loop
    float a0, a1, a2, a3;
    {
        float2 f0 = __half22float2(sv.lo), f1 = __half22float2(sv.hi);
        a0 = f0.x; a1 = f0.y; a2 = f1.x; a3 = f1.y;
    }

    int beg = row_ptr[d];
    int end = rend[d];
    if (beg < end) {
        int4 ia = *(const int4*)&csr_src[beg];
        int4 ib = *(const int4*)&csr_src[beg + 4];
        int jb = beg;
        for (;;) {
            int jn = jb + 8;
            bool more = jn < end;
            int js = more ? jn : beg;
            int4 na = *(const int4*)&csr_src[js];
            int4 nb = *(const int4*)&csr_src[js + 4];
            half4 v0 = xrow[(size_t)ia.x * 4];
            half4 v1 = xrow[(size_t)ia.y * 4];
            half4 v2 = xrow[(size_t)ia.z * 4];
            half4 v3 = xrow[(size_t)ia.w * 4];
            half4 v4 = xrow[(size_t)ib.x * 4];
            half4 v5 = xrow[(size_t)ib.y * 4];
            half4 v6 = xrow[(size_t)ib.z * 4];
            half4 v7 = xrow[(size_t)ib.w * 4];
            ACC4(v0); ACC4(v1); ACC4(v2); ACC4(v3);
            ACC4(v4); ACC4(v5); ACC4(v6); ACC4(v7);
            if (!more) break;
            jb = jn; ia = na; ib = nb;
        }
    }

    float di = dinv[d];
    float4 bv = *(const float4*)&b2s[4 * c];
    float4 r;
    r.x = fmaf(di, a0, bv.x);
    r.y = fmaf(di, a1, bv.y);
    r.z = fmaf(di, a2, bv.z);
    r.w = fmaf(di, a3, bv.w);
    *(float4*)&outp[(size_t)d * 32 + 4 * c] = r;
}

extern "C" void kernel_launch(void* const* d_in, const int* in_sizes, int n_in,
                              void* d_out, int out_size, void* d_ws, size_t ws_size,
                              hipStream_t stream) {
    const float* x  = (const float*)d_in[0];   // [n, 64]
    const int*   ei = (const int*)d_in[1];     // [2, E]
    const float* W1 = (const float*)d_in[2];   // [64, 64]
    const float* b1 = (const float*)d_in[3];   // [64]
    const float* W2 = (const float*)d_in[4];   // [64, 32]
    const float* b2 = (const float*)d_in[5];   // [32]
    float* out = (float*)d_out;                // [n, 32]

    const int n = in_sizes[0] / N_FEAT_IN;     // 100000
    const int E = in_sizes[1] / 2;             // 1600000
    const int* srcI = ei;
    const int* dstI = ei + E;

    const int NB = (n + 511) >> B2SHIFT;       // 196 coarse buckets
    const int NR = (E + CHUNK - 1) / CHUNK;    // 391 chunks

    // workspace layout (256B aligned)
    char* ws = (char*)d_ws;
    size_t off = 0;
    auto alloc = [&](size_t bytes) {
        void* p = ws + off;
        off += (bytes + 255) & ~(size_t)255;
        return p;
    };
    float*    dinv    = (float*)alloc((size_t)n * 4);
    int*      row_ptr = (int*)alloc((size_t)(n + 1) * 4);
    int*      rend    = (int*)alloc((size_t)n * 4);
    int*      bbase   = (int*)alloc((size_t)(NB + 1) * 4);
    int*      ctot    = (int*)alloc((size_t)256 * 4);
    int*      cbase   = (int*)alloc((size_t)256 * 4);
    int*      H       = (int*)alloc((size_t)NR * 256 * 4);        // ~400KB
    unsigned* bedges  = (unsigned*)alloc((size_t)E * 4);
    int*      csr_src = (int*)alloc((size_t)(E + (size_t)NB * PADSTRIDE + 16) * 4);
    __half*   xs1     = (__half*)alloc((size_t)(n + 1) * 64 * 2); // 4 slabs [n+1][16]
    __half*   th      = (__half*)alloc((size_t)n * 64 * 2);       // 4 slabs [n][16]
    __half*   xs2     = (__half*)alloc((size_t)(n + 1) * 32 * 2); // 2 slabs [n+1][16]

    const size_t slab1 = (size_t)(n + 1) * 16;   // xs1/xs2 slab elems
    const size_t slabT = (size_t)n * 16;         // th slab elems

    // 1) atomic-free bucket sort by dst>>9 (R14 verbatim, ~27us incl. csr)
    passA_hist<<<NR, 1024, 0, stream>>>(dstI, H, E);
    col_scan_a<<<256, 512, 0, stream>>>(H, ctot, NR);
    col_scan_b<<<1, 256, 0, stream>>>(ctot, cbase, bbase, row_ptr, NB, n, E);
    passB_place<<<NR, 1024, 0, stream>>>(srcI, dstI, H, cbase, bedges, E);

    // 2) merged: padded row_ptr/rend + dinv + CSR scatter (+pad fill)
    bucket_csr<<<NB, 1024, 0, stream>>>(bbase, bedges, row_ptr, rend, dinv, csr_src, n);

    // 3) layer 1 GEMM: xs1 slabs = half(dinv .* (X W1))
    gemm64<<<(n + 63) / 64, 256, 0, stream>>>(x, W1, dinv, xs1, n);

    // 4) layer-1 aggregate, 4 sequential L2-resident slab passes
    for (int f = 0; f < 4; ++f)
        agg64s<<<(n + 63) / 64, 256, 0, stream>>>(row_ptr, rend, csr_src, dinv,
                                                  xs1 + (size_t)f * slab1,
                                                  b1 + 16 * f,
                                                  th + (size_t)f * slabT, n);

    // 5) layer-2 transform: xs2 slabs = half(dinv .* (t W2))
    gemm32h<<<(n + 63) / 64, 256, 0, stream>>>(th, W2, dinv, xs2, n);

    // 6) layer-2 aggregate, 2 slab passes -> out
    for (int s = 0; s < 2; ++s)
        agg32s<<<(n + 63) / 64, 256, 0, stream>>>(row_ptr, rend, csr_src, dinv,
                                                  xs2 + (size_t)s * slab1,
                                                  b2 + 16 * s,
                                                  out + 16 * s, n);
}

// Round 4
// 198.269 us; speedup vs baseline: 1.6112x; 1.2375x over previous
//
#include <hip/hip_runtime.h>
#include <hip/hip_bf16.h>
#include <hip/hip_fp16.h>

// GCN 2-layer: out = Ahat * relu(Ahat*(X W1)+b1) * W2 + b2
// Round 17: R14 aggs (proven) + register-tiled GEMMs + atomic-base build.
//  - build: init(zero gcur) -> place(LDS hist + global atomic bucket base +
//    scatter into static CAP-strided bucket regions) -> bucket_csr (R14 body,
//    beg = b*CAP). 3 dispatches instead of 5; no grid.sync (R15 lesson).
//  - gemm64/gemm32h: 4x8 thread tile, A staged TRANSPOSED in LDS so inner
//    loop is 1 a-float4 + 2 w-float4 per 4x8x1 FMA block (LDS bytes/FMA
//    0.375 vs 1.06) -> LDS-BW-bound 25us -> ~10us. Same k-order per output
//    => bitwise-identical results.
//  - agg64/agg32: R14 verbatim (padded CSR half8 gathers; mem-system-bound).

#define N_FEAT_IN 64
#define B2SHIFT 9        // 512 dst nodes per coarse bucket
#define CHUNK 4096       // edges per block in place
#define CAP 12288        // bedges bucket region capacity (mean 8163 + 45 sigma)
#define CSRCAP 16384     // csr_src bucket region capacity (CAP + 512*7 pad, 8-al)

struct alignas(8) half4 { __half2 lo, hi; };
struct alignas(16) half8 { __half2 h[4]; };

// ---- init: zero the global bucket cursors ----
__global__ __launch_bounds__(256) void init_k(int* __restrict__ gcur) {
    gcur[threadIdx.x] = 0;
}

// ---- place: per-chunk LDS hist -> global atomic base -> scatter ----
__global__ __launch_bounds__(1024) void place_k(const int* __restrict__ src,
                                                const int* __restrict__ dst,
                                                int* __restrict__ gcur,
                                                unsigned* __restrict__ bedges, int E) {
    __shared__ int h[256];
    __shared__ int cur[256];
    int t = threadIdx.x;
    if (t < 256) h[t] = 0;
    __syncthreads();
    int base = blockIdx.x * CHUNK;
    int end = min(base + CHUNK, E);
    for (int i = base + t; i < end; i += 1024)
        atomicAdd(&h[dst[i] >> B2SHIFT], 1);
    __syncthreads();
    if (t < 256) {
        int cnt = h[t];
        int b0 = cnt ? atomicAdd(&gcur[t], cnt) : 0;  // device-scope
        cur[t] = t * CAP + b0;
    }
    __syncthreads();
    for (int i = base + t; i < end; i += 1024) {
        int d = dst[i];
        int p = atomicAdd(&cur[d >> B2SHIFT], 1);     // LDS atomic
        bedges[p] = ((unsigned)src[i] << B2SHIFT) | (unsigned)(d & 511);
    }
}

// ---- bucket_csr: hist -> padded scan -> row_ptr/rend/dinv -> scatter ----
__global__ __launch_bounds__(1024) void bucket_csr(const int* __restrict__ gcnt,
                                                   const unsigned* __restrict__ bedges,
                                                   int* __restrict__ row_ptr,
                                                   int* __restrict__ rend,
                                                   float* __restrict__ dinv,
                                                   int* __restrict__ csr_src, int n) {
    __shared__ int lh[512];
    __shared__ int cur[512];
    int t = threadIdx.x;
    if (t < 512) lh[t] = 0;
    __syncthreads();
    int b = blockIdx.x;
    int beg = b * CAP;
    int end = beg + gcnt[b];
    for (int i = beg + t; i < end; i += 1024)
        atomicAdd(&lh[bedges[i] & 511], 1);
    __syncthreads();
    int c = (t < 512) ? lh[t] : 0;       // true degree (no self-loop)
    __syncthreads();
    int cp = (c + 7) & ~7;               // padded degree
    if (t < 512) lh[t] = cp;
    __syncthreads();
    for (int off = 1; off < 512; off <<= 1) {
        int a = (t < 512 && t >= off) ? lh[t - off] : 0;
        __syncthreads();
        if (t < 512) lh[t] += a;
        __syncthreads();
    }
    int pb = b * CSRCAP;                 // 8-aligned bucket csr base
    if (t < 512) {
        int d = (b << B2SHIFT) + t;
        int rbeg = pb + lh[t] - cp;      // 8-aligned exclusive padded offset
        cur[t] = rbeg;
        if (d < n) {
            row_ptr[d] = rbeg;
            rend[d] = rbeg + cp;
            dinv[d] = rsqrtf((float)c + 1.0f);
            for (int i = c; i < cp; ++i) csr_src[rbeg + i] = n;  // pad -> zero row
        }
    }
    __syncthreads();
    for (int i = beg + t; i < end; i += 1024) {
        unsigned v = bedges[i];
        int p = atomicAdd(&cur[v & 511], 1);  // LDS atomic
        csr_src[p] = (int)(v >> B2SHIFT);
    }
}

// ---- gemm64: xs1[n+1][64] fp16 = half( dinv[row] * (X W1) ) ----
// 128 rows/block, thread tile 4 rows x 8 cols, A transposed in LDS.
__global__ __launch_bounds__(256) void gemm64(const float* __restrict__ A,
                                              const float* __restrict__ W,
                                              const float* __restrict__ dinv,
                                              __half* __restrict__ outh, int n) {
    __shared__ float AsT[64][132];   // [k][row], stride 528B (16B aligned)
    __shared__ float Ws[64][64];

    const int t = threadIdx.x;
    const int r0 = blockIdx.x * 128;

    if (blockIdx.x == 0 && t < 64)   // zero pad row n
        outh[(size_t)n * 64 + t] = __float2half(0.f);

    for (int i = t; i < 64 * 16; i += 256) {
        int k = i >> 4;
        int c4 = (i & 15) * 4;
        *(float4*)&Ws[k][c4] = *(const float4*)&W[k * 64 + c4];
    }
    for (int i = t; i < 128 * 16; i += 256) {
        int row = i >> 4;
        int c4 = (i & 15) * 4;
        int g = r0 + row;
        float4 v = make_float4(0.f, 0.f, 0.f, 0.f);
        if (g < n) v = *(const float4*)&A[(size_t)g * 64 + c4];
        AsT[c4 + 0][row] = v.x;
        AsT[c4 + 1][row] = v.y;
        AsT[c4 + 2][row] = v.z;
        AsT[c4 + 3][row] = v.w;
    }
    __syncthreads();

    const int rg = t >> 3;           // 0..31 -> rows rg*4..+3
    const int cg = t & 7;            // 0..7  -> cols cg*8..+7
    float acc[4][8];
#pragma unroll
    for (int r = 0; r < 4; ++r)
#pragma unroll
        for (int j = 0; j < 8; ++j) acc[r][j] = 0.f;

#pragma unroll 4
    for (int k = 0; k < 64; ++k) {
        float4 a = *(const float4*)&AsT[k][rg * 4];
        float4 w0 = *(const float4*)&Ws[k][cg * 8];
        float4 w1 = *(const float4*)&Ws[k][cg * 8 + 4];
        float av[4] = {a.x, a.y, a.z, a.w};
        float wv[8] = {w0.x, w0.y, w0.z, w0.w, w1.x, w1.y, w1.z, w1.w};
#pragma unroll
        for (int r = 0; r < 4; ++r)
#pragma unroll
            for (int j = 0; j < 8; ++j)
                acc[r][j] = fmaf(av[r], wv[j], acc[r][j]);
    }

#pragma unroll
    for (int r = 0; r < 4; ++r) {
        int g = r0 + rg * 4 + r;
        if (g < n) {
            float sc = dinv[g];
            half8 h;
            h.h[0] = __floats2half2_rn(acc[r][0] * sc, acc[r][1] * sc);
            h.h[1] = __floats2half2_rn(acc[r][2] * sc, acc[r][3] * sc);
            h.h[2] = __floats2half2_rn(acc[r][4] * sc, acc[r][5] * sc);
            h.h[3] = __floats2half2_rn(acc[r][6] * sc, acc[r][7] * sc);
            *(half8*)&outh[(size_t)g * 64 + cg * 8] = h;
        }
    }
}

#define ACC8(v)                                                       \
    {                                                                 \
        float2 f0 = __half22float2((v).h[0]);                         \
        float2 f1 = __half22float2((v).h[1]);                         \
        float2 f2 = __half22float2((v).h[2]);                         \
        float2 f3 = __half22float2((v).h[3]);                         \
        a0 += f0.x; a1 += f0.y; a2 += f1.x; a3 += f1.y;               \
        a4 += f2.x; a5 += f2.y; a6 += f3.x; a7 += f3.y;               \
    }

// ---- agg64: 8 rows/wave, 8 lanes/row, half8/lane; t = relu(dinv*acc+b1) ----
__global__ __launch_bounds__(256) void agg64(const int* __restrict__ row_ptr,
                                             const int* __restrict__ rend,
                                             const int* __restrict__ csr_src,
                                             const float* __restrict__ dinv,
                                             const __half* __restrict__ xs1,
                                             const float* __restrict__ b1,
                                             __half* __restrict__ th, int n) {
    int d = blockIdx.x * 32 + (threadIdx.x >> 3);  // 32 rows/block
    if (d >= n) return;
    int c = threadIdx.x & 7;                       // half8 slice (feats 8c..8c+7)
    const half8* __restrict__ xrow = (const half8*)xs1 + c;  // row stride 8 half8

    half8 sv = xrow[(size_t)d * 8];                // self-loop
    float a0, a1, a2, a3, a4, a5, a6, a7;
    {
        float2 f0 = __half22float2(sv.h[0]), f1 = __half22float2(sv.h[1]);
        float2 f2 = __half22float2(sv.h[2]), f3 = __half22float2(sv.h[3]);
        a0 = f0.x; a1 = f0.y; a2 = f1.x; a3 = f1.y;
        a4 = f2.x; a5 = f2.y; a6 = f3.x; a7 = f3.y;
    }

    int beg = row_ptr[d];
    int end = rend[d];
    if (beg < end) {
        int4 ia = *(const int4*)&csr_src[beg];
        int4 ib = *(const int4*)&csr_src[beg + 4];
        int jb = beg;
        for (;;) {
            int jn = jb + 8;
            bool more = jn < end;
            int js = more ? jn : beg;              // prefetch next batch
            int4 na = *(const int4*)&csr_src[js];
            int4 nb = *(const int4*)&csr_src[js + 4];
            half8 v0 = xrow[(size_t)ia.x * 8];
            half8 v1 = xrow[(size_t)ia.y * 8];
            half8 v2 = xrow[(size_t)ia.z * 8];
            half8 v3 = xrow[(size_t)ia.w * 8];
            half8 v4 = xrow[(size_t)ib.x * 8];
            half8 v5 = xrow[(size_t)ib.y * 8];
            half8 v6 = xrow[(size_t)ib.z * 8];
            half8 v7 = xrow[(size_t)ib.w * 8];
            ACC8(v0); ACC8(v1); ACC8(v2); ACC8(v3);
            ACC8(v4); ACC8(v5); ACC8(v6); ACC8(v7);
            if (!more) break;
            jb = jn; ia = na; ib = nb;
        }
    }

    float di = dinv[d];
    float4 ba = *(const float4*)&b1[8 * c];
    float4 bb = *(const float4*)&b1[8 * c + 4];
    float t0 = fmaxf(fmaf(di, a0, ba.x), 0.f);
    float t1 = fmaxf(fmaf(di, a1, ba.y), 0.f);
    float t2 = fmaxf(fmaf(di, a2, ba.z), 0.f);
    float t3 = fmaxf(fmaf(di, a3, ba.w), 0.f);
    float t4 = fmaxf(fmaf(di, a4, bb.x), 0.f);
    float t5 = fmaxf(fmaf(di, a5, bb.y), 0.f);
    float t6 = fmaxf(fmaf(di, a6, bb.z), 0.f);
    float t7 = fmaxf(fmaf(di, a7, bb.w), 0.f);
    half8 o;
    o.h[0] = __floats2half2_rn(t0, t1);
    o.h[1] = __floats2half2_rn(t2, t3);
    o.h[2] = __floats2half2_rn(t4, t5);
    o.h[3] = __floats2half2_rn(t6, t7);
    *(half8*)&th[(size_t)d * 64 + 8 * c] = o;
}

// ---- gemm32h: xs2[n+1][32] fp16 = half( dinv[row] * (t W2) ) ----
// 256 rows/block, thread tile 4 rows x 8 cols, A transposed in LDS.
__global__ __launch_bounds__(256) void gemm32h(const __half* __restrict__ Ah,
                                               const float* __restrict__ W,
                                               const float* __restrict__ dinv,
                                               __half* __restrict__ outh, int n) {
    __shared__ float AsT[64][260];   // [k][row], stride 1040B (16B aligned)
    __shared__ float Ws[64][32];

    const int t = threadIdx.x;
    const int r0 = blockIdx.x * 256;

    if (blockIdx.x == 0 && t < 32)   // zero pad row n
        outh[(size_t)n * 32 + t] = __float2half(0.f);

    for (int i = t; i < 64 * 8; i += 256) {
        int k = i >> 3;
        int c4 = (i & 7) * 4;
        *(float4*)&Ws[k][c4] = *(const float4*)&W[k * 32 + c4];
    }
    for (int i = t; i < 256 * 8; i += 256) {
        int row = i >> 3;
        int c8 = (i & 7) * 8;
        int g = r0 + row;
        if (g < n) {
            half8 hv = *(const half8*)&Ah[(size_t)g * 64 + c8];
            float2 f0 = __half22float2(hv.h[0]), f1 = __half22float2(hv.h[1]);
            float2 f2 = __half22float2(hv.h[2]), f3 = __half22float2(hv.h[3]);
            AsT[c8 + 0][row] = f0.x; AsT[c8 + 1][row] = f0.y;
            AsT[c8 + 2][row] = f1.x; AsT[c8 + 3][row] = f1.y;
            AsT[c8 + 4][row] = f2.x; AsT[c8 + 5][row] = f2.y;
            AsT[c8 + 6][row] = f3.x; AsT[c8 + 7][row] = f3.y;
        } else {
#pragma unroll
            for (int j = 0; j < 8; ++j) AsT[c8 + j][row] = 0.f;
        }
    }
    __syncthreads();

    const int rg = t >> 2;           // 0..63 -> rows rg*4..+3
    const int cg = t & 3;            // 0..3  -> cols cg*8..+7
    float acc[4][8];
#pragma unroll
    for (int r = 0; r < 4; ++r)
#pragma unroll
        for (int j = 0; j < 8; ++j) acc[r][j] = 0.f;

#pragma unroll 4
    for (int k = 0; k < 64; ++k) {
        float4 a = *(const float4*)&AsT[k][rg * 4];
        float4 w0 = *(const float4*)&Ws[k][cg * 8];
        float4 w1 = *(const float4*)&Ws[k][cg * 8 + 4];
        float av[4] = {a.x, a.y, a.z, a.w};
        float wv[8] = {w0.x, w0.y, w0.z, w0.w, w1.x, w1.y, w1.z, w1.w};
#pragma unroll
        for (int r = 0; r < 4; ++r)
#pragma unroll
            for (int j = 0; j < 8; ++j)
                acc[r][j] = fmaf(av[r], wv[j], acc[r][j]);
    }

#pragma unroll
    for (int r = 0; r < 4; ++r) {
        int g = r0 + rg * 4 + r;
        if (g < n) {
            float sc = dinv[g];
            half8 h;
            h.h[0] = __floats2half2_rn(acc[r][0] * sc, acc[r][1] * sc);
            h.h[1] = __floats2half2_rn(acc[r][2] * sc, acc[r][3] * sc);
            h.h[2] = __floats2half2_rn(acc[r][4] * sc, acc[r][5] * sc);
            h.h[3] = __floats2half2_rn(acc[r][6] * sc, acc[r][7] * sc);
            *(half8*)&outh[(size_t)g * 32 + cg * 8] = h;
        }
    }
}

// ---- agg32: 16 rows/wave, 4 lanes/row, half8/lane; out = dinv*acc + b2 ----
__global__ __launch_bounds__(256) void agg32(const int* __restrict__ row_ptr,
                                             const int* __restrict__ rend,
                                             const int* __restrict__ csr_src,
                                             const float* __restrict__ dinv,
                                             const __half* __restrict__ xs2,
                                             const float* __restrict__ b2,
                                             float* __restrict__ out, int n) {
    int d = blockIdx.x * 64 + (threadIdx.x >> 2);  // 64 rows/block
    if (d >= n) return;
    int c = threadIdx.x & 3;                       // half8 slice (feats 8c..8c+7)
    const half8* __restrict__ xrow = (const half8*)xs2 + c;  // row stride 4 half8

    half8 sv = xrow[(size_t)d * 4];                // self-loop
    float a0, a1, a2, a3, a4, a5, a6, a7;
    {
        float2 f0 = __half22float2(sv.h[0]), f1 = __half22float2(sv.h[1]);
        float2 f2 = __half22float2(sv.h[2]), f3 = __half22float2(sv.h[3]);
        a0 = f0.x; a1 = f0.y; a2 = f1.x; a3 = f1.y;
        a4 = f2.x; a5 = f2.y; a6 = f3.x; a7 = f3.y;
    }

    int beg = row_ptr[d];
    int end = rend[d];
    if (beg < end) {
        int4 ia = *(const int4*)&csr_src[beg];
        int4 ib = *(const int4*)&csr_src[beg + 4];
        int jb = beg;
        for (;;) {
            int jn = jb + 8;
            bool more = jn < end;
            int js = more ? jn : beg;
            int4 na = *(const int4*)&csr_src[js];
            int4 nb = *(const int4*)&csr_src[js + 4];
            half8 v0 = xrow[(size_t)ia.x * 4];
            half8 v1 = xrow[(size_t)ia.y * 4];
            half8 v2 = xrow[(size_t)ia.z * 4];
            half8 v3 = xrow[(size_t)ia.w * 4];
            half8 v4 = xrow[(size_t)ib.x * 4];
            half8 v5 = xrow[(size_t)ib.y * 4];
            half8 v6 = xrow[(size_t)ib.z * 4];
            half8 v7 = xrow[(size_t)ib.w * 4];
            ACC8(v0); ACC8(v1); ACC8(v2); ACC8(v3);
            ACC8(v4); ACC8(v5); ACC8(v6); ACC8(v7);
            if (!more) break;
            jb = jn; ia = na; ib = nb;
        }
    }

    float di = dinv[d];
    float4 ba = *(const float4*)&b2[8 * c];
    float4 bb = *(const float4*)&b2[8 * c + 4];
    float4 r0, r1;
    r0.x = fmaf(di, a0, ba.x);
    r0.y = fmaf(di, a1, ba.y);
    r0.z = fmaf(di, a2, ba.z);
    r0.w = fmaf(di, a3, ba.w);
    r1.x = fmaf(di, a4, bb.x);
    r1.y = fmaf(di, a5, bb.y);
    r1.z = fmaf(di, a6, bb.z);
    r1.w = fmaf(di, a7, bb.w);
    *(float4*)&out[(size_t)d * 32 + 8 * c] = r0;
    *(float4*)&out[(size_t)d * 32 + 8 * c + 4] = r1;
}

extern "C" void kernel_launch(void* const* d_in, const int* in_sizes, int n_in,
                              void* d_out, int out_size, void* d_ws, size_t ws_size,
                              hipStream_t stream) {
    const float* x  = (const float*)d_in[0];   // [n, 64]
    const int*   ei = (const int*)d_in[1];     // [2, E]
    const float* W1 = (const float*)d_in[2];   // [64, 64]
    const float* b1 = (const float*)d_in[3];   // [64]
    const float* W2 = (const float*)d_in[4];   // [64, 32]
    const float* b2 = (const float*)d_in[5];   // [32]
    float* out = (float*)d_out;                // [n, 32]

    const int n = in_sizes[0] / N_FEAT_IN;     // 100000
    const int E = in_sizes[1] / 2;             // 1600000
    const int* srcI = ei;
    const int* dstI = ei + E;

    const int NB = (n + 511) >> B2SHIFT;       // 196 coarse buckets
    const int NR = (E + CHUNK - 1) / CHUNK;    // 391 chunks

    // workspace layout (256B aligned)
    char* ws = (char*)d_ws;
    size_t off = 0;
    auto alloc = [&](size_t bytes) {
        void* p = ws + off;
        off += (bytes + 255) & ~(size_t)255;
        return p;
    };
    float*    dinv    = (float*)alloc((size_t)n * 4);
    int*      row_ptr = (int*)alloc((size_t)(n + 1) * 4);
    int*      rend    = (int*)alloc((size_t)n * 4);
    int*      gcur    = (int*)alloc((size_t)256 * 4);
    unsigned* bedges  = (unsigned*)alloc((size_t)NB * CAP * 4);     // 9.6MB
    int*      csr_src = (int*)alloc((size_t)NB * CSRCAP * 4);       // 12.8MB
    __half*   xs1     = (__half*)alloc((size_t)(n + 1) * 64 * 2);   // +pad row
    __half*   th      = (__half*)alloc((size_t)n * 64 * 2);
    __half*   xs2     = (__half*)alloc((size_t)(n + 1) * 32 * 2);   // +pad row

    // 1) build: init cursors -> place into CAP-strided buckets -> CSR
    init_k<<<1, 256, 0, stream>>>(gcur);
    place_k<<<NR, 1024, 0, stream>>>(srcI, dstI, gcur, bedges, E);
    bucket_csr<<<NB, 1024, 0, stream>>>(gcur, bedges, row_ptr, rend, dinv, csr_src, n);

    // 2) layer 1 GEMM: xs1 = half(dinv .* (X W1))
    gemm64<<<(n + 127) / 128, 256, 0, stream>>>(x, W1, dinv, xs1, n);

    // 3) layer-1 aggregate: t = relu(dinv*(gather+self) + b1)
    agg64<<<(n + 31) / 32, 256, 0, stream>>>(row_ptr, rend, csr_src, dinv, xs1, b1, th, n);

    // 4) layer-2 transform: xs2 = half(dinv .* (t W2))
    gemm32h<<<(n + 255) / 256, 256, 0, stream>>>(th, W2, dinv, xs2, n);

    // 5) layer-2 aggregate -> out
    agg32<<<(n + 63) / 64, 256, 0, stream>>>(row_ptr, rend, csr_src, dinv, xs2, b2, out, n);
}